// Round 4
// baseline (132.700 us; speedup 1.0000x reference)
//
#include <hip/hip_runtime.h>
#include <hip/hip_bf16.h>

#define OUT_N 8192
#define IN_K  8192
#define M_ROWS 64

typedef __attribute__((ext_vector_type(8))) short  bf16x8;
typedef __attribute__((ext_vector_type(4))) float  f32x4;
typedef __attribute__((ext_vector_type(4))) int    int4v;

__device__ const float NF4_TAB[16] = {
  -1.0f, -0.6961928009986877f, -0.5250730514526367f, -0.39491748809814453f,
  -0.28444138169288635f, -0.18477343022823334f, -0.09105003625154495f, 0.0f,
  0.07958029955625534f, 0.16093020141124725f, 0.24611230850219726f,
  0.33791524171829224f, 0.44070982933044434f, 0.5626170039176941f,
  0.7229568362236023f, 1.0f };

static __device__ __forceinline__ unsigned short f2bf(float f) {
  union { __hip_bfloat16 h; unsigned short s; } u;
  u.h = __float2bfloat16(f);
  return u.s;
}

// Repack x (fp32 [64][8192]) -> bf16 MFMA A-fragment order.
// xf[((ks*4 + mt)*64 + lane)*8 + j] = bf16(x[mt*16+(lane&15)][ks*32+(lane>>4)*8+j])
__global__ __launch_bounds__(256) void qlin_prep(const float* __restrict__ x,
                                                 unsigned short* __restrict__ xf) {
  int t = blockIdx.x * 256 + threadIdx.x;          // (ks, mt, lane)
  int lane = t & 63, mt = (t >> 6) & 3, ks = t >> 8;
  int ri = lane & 15, kbb = lane >> 4;
  const float* src = x + (size_t)(mt * 16 + ri) * IN_K + ks * 32 + kbb * 8;
  f32x4 a = *(const f32x4*)src;
  f32x4 c = *(const f32x4*)(src + 4);
  bf16x8 o;
  o[0] = (short)f2bf(a[0]); o[1] = (short)f2bf(a[1]);
  o[2] = (short)f2bf(a[2]); o[3] = (short)f2bf(a[3]);
  o[4] = (short)f2bf(c[0]); o[5] = (short)f2bf(c[1]);
  o[6] = (short)f2bf(c[2]); o[7] = (short)f2bf(c[3]);
  ((bf16x8*)xf)[t] = o;
}

// Fused NF4 dequant + GEMM. No barriers, no LDS staging.
// Dequant = 1 LDS pair-LUT read per byte (value is a ready bf16 pair).
// absmax applied per 64-k group on the f32 accumulator (deferred scaling).
template<int NC>
__global__ __launch_bounds__(256, 4) void qlin_main(
    const int*   __restrict__ packed,
    const float* __restrict__ absmax,
    const unsigned short* __restrict__ xf,
    unsigned short* __restrict__ parts) {
  constexpr int KCn = IN_K / NC;      // k per chunk
  constexpr int NIT = KCn / 32;       // k-steps per chunk
  constexpr int LOG = (NC == 8) ? 3 : 2;

  __shared__ unsigned int lut[256];   // byte -> packed {bf16(nf4[lo]), bf16(nf4[hi])}
  {
    int t = threadIdx.x;
    unsigned lo = f2bf(NF4_TAB[t & 15]);
    unsigned hi = f2bf(NF4_TAB[(t >> 4) & 15]);
    lut[t] = lo | (hi << 16);
  }
  __syncthreads();

  const int l     = threadIdx.x & 63;
  const int w     = threadIdx.x >> 6;
  const int ntile = (int)blockIdx.x >> LOG;
  const int chunk = (int)blockIdx.x & (NC - 1);
  const int col   = ntile * 64 + w * 16 + (l & 15);
  const int kb    = l >> 4;
  const int kc0   = chunk * KCn;
  const int ksg0  = kc0 >> 5;

  const char* pbase = (const char*)packed
                    + ((size_t)col * (IN_K / 2) + kc0 / 2) * 4 + kb * 16;
  const char* xbase = (const char*)xf + (size_t)ksg0 * 4096 + l * 16;
  const f32x4* aptr4 = (const f32x4*)(absmax + (size_t)col * 128 + (kc0 >> 6));

  // prologue: pk 4-deep, A 1-deep, first absmax quad
  int4v pk[4];
  #pragma unroll
  for (int i = 0; i < 4; ++i) pk[i] = *(const int4v*)(pbase + i * 64);
  bf16x8 A[4];
  #pragma unroll
  for (int mt = 0; mt < 4; ++mt) A[mt] = *(const bf16x8*)(xbase + mt * 1024);
  f32x4 amx = aptr4[0], amxn = amx;

  const f32x4 zro = {0.f, 0.f, 0.f, 0.f};
  f32x4 mn[4] = {zro, zro, zro, zro};
  f32x4 sb[4];

  #pragma unroll
  for (int u = 0; u < NIT; ++u) {
    // ---- early-issue prefetches (A before pk: in-order retirement safety)
    const int ak = (u + 1 < NIT) ? u + 1 : NIT - 1;
    const int sk = (u + 4 < NIT) ? u + 4 : NIT - 1;
    bf16x8 nA0 = *(const bf16x8*)(xbase + (size_t)ak * 4096 + 0 * 1024);
    bf16x8 nA1 = *(const bf16x8*)(xbase + (size_t)ak * 4096 + 1 * 1024);
    bf16x8 nA2 = *(const bf16x8*)(xbase + (size_t)ak * 4096 + 2 * 1024);
    bf16x8 nA3 = *(const bf16x8*)(xbase + (size_t)ak * 4096 + 3 * 1024);
    int4v npk = *(const int4v*)(pbase + (size_t)sk * 64);
    if ((u & 7) == 0) {
      int aq = (u >> 3) + 1;
      if (aq > NIT / 8 - 1) aq = NIT / 8 - 1;
      amxn = aptr4[aq];
    }

    // ---- dequant: 4 pair-LUT reads, zero arithmetic
    int4v cur = pk[u & 3];
    int4v bw;
    #pragma unroll
    for (int i = 0; i < 4; ++i) bw[i] = (int)lut[cur[i] & 255];
    union { int4v i; bf16x8 h; } cvt; cvt.i = bw;
    const bf16x8 b = cvt.h;

    // ---- MFMA into 64-k group sub-acc; fold amax on group close
    if ((u & 1) == 0) {
      #pragma unroll
      for (int mt = 0; mt < 4; ++mt)
        sb[mt] = __builtin_amdgcn_mfma_f32_16x16x32_bf16(A[mt], b, zro, 0, 0, 0);
    } else {
      #pragma unroll
      for (int mt = 0; mt < 4; ++mt)
        sb[mt] = __builtin_amdgcn_mfma_f32_16x16x32_bf16(A[mt], b, sb[mt], 0, 0, 0);
      const float am = amx[(u >> 1) & 3];
      #pragma unroll
      for (int mt = 0; mt < 4; ++mt)
        mn[mt] += sb[mt] * am;
    }

    // ---- rotate prefetches in (SSA; regalloc coalesces)
    A[0] = nA0; A[1] = nA1; A[2] = nA2; A[3] = nA3;
    pk[u & 3] = npk;
    if ((u & 7) == 7) amx = amxn;
  }

  // epilogue: D mapping col=lane&15, row=(lane>>4)*4+reg; bf16 partials
  unsigned short* po = parts + (size_t)chunk * M_ROWS * OUT_N + col;
  const int rbase = kb * 4;
  #pragma unroll
  for (int mt = 0; mt < 4; ++mt) {
    #pragma unroll
    for (int r = 0; r < 4; ++r)
      po[(size_t)(mt * 16 + rbase + r) * OUT_N] = f2bf(mn[mt][r]);
  }
}

template<int NC>
__global__ __launch_bounds__(256) void qlin_reduce(
    const unsigned short* __restrict__ parts,
    const float* __restrict__ bias,
    float*       __restrict__ out) {
  int t = blockIdx.x * 256 + threadIdx.x;          // one thread = 8 outputs
  if (t >= M_ROWS * OUT_N / 8) return;
  const size_t off = (size_t)t * 8;
  float s[8] = {0,0,0,0,0,0,0,0};
  #pragma unroll
  for (int c = 0; c < NC; ++c) {
    bf16x8 v = *(const bf16x8*)(parts + (size_t)c * M_ROWS * OUT_N + off);
    #pragma unroll
    for (int j = 0; j < 8; ++j)
      s[j] += __uint_as_float(((unsigned)(unsigned short)v[j]) << 16);
  }
  const int colb = t & (OUT_N / 8 - 1);
  const f32x4* bp = (const f32x4*)(bias + colb * 8);
  f32x4 b0 = bp[0], b1 = bp[1];
  f32x4 o0, o1;
  o0[0] = s[0] + b0[0]; o0[1] = s[1] + b0[1];
  o0[2] = s[2] + b0[2]; o0[3] = s[3] + b0[3];
  o1[0] = s[4] + b1[0]; o1[1] = s[5] + b1[1];
  o1[2] = s[6] + b1[2]; o1[3] = s[7] + b1[3];
  *(f32x4*)(out + off) = o0;
  *(f32x4*)(out + off + 4) = o1;
}

extern "C" void kernel_launch(void* const* d_in, const int* in_sizes, int n_in,
                              void* d_out, int out_size, void* d_ws, size_t ws_size,
                              hipStream_t stream) {
  const float* x      = (const float*)d_in[0];
  const int*   packed = (const int*)d_in[1];
  const float* absmax = (const float*)d_in[2];
  const float* bias   = (const float*)d_in[3];
  float* out = (float*)d_out;

  unsigned short* xf    = (unsigned short*)d_ws;                // 1 MB
  unsigned short* parts = (unsigned short*)((char*)d_ws + (1 << 20)); // NC MB (bf16)

  qlin_prep<<<(M_ROWS * IN_K / 8 + 255) / 256, 256, 0, stream>>>(x, xf);

  const size_t need8 = (size_t)(1 << 20)
                     + (size_t)8 * M_ROWS * OUT_N * sizeof(unsigned short);
  if (ws_size >= need8) {
    qlin_main<8><<<(OUT_N / 64) * 8, 256, 0, stream>>>(packed, absmax, xf, parts);
    qlin_reduce<8><<<(M_ROWS * OUT_N / 8 + 255) / 256, 256, 0, stream>>>(parts, bias, out);
  } else {
    qlin_main<4><<<(OUT_N / 64) * 4, 256, 0, stream>>>(packed, absmax, xf, parts);
    qlin_reduce<4><<<(M_ROWS * OUT_N / 8 + 255) / 256, 256, 0, stream>>>(parts, bias, out);
  }
}